// Round 6
// baseline (250.158 us; speedup 1.0000x reference)
//
#include <hip/hip_runtime.h>
#include <cstddef>

#define LEN    1024
#define DIN    512
#define NHEAD  8
#define HDIM   64
#define BATCH  8

typedef __attribute__((ext_vector_type(8))) short  short8;
typedef __attribute__((ext_vector_type(4))) float  f32x4;

#define MFMA16(a, b, c) __builtin_amdgcn_mfma_f32_16x16x32_bf16((a), (b), (c), 0, 0, 0)
#define PERM_HI 0x07060302u   // dest = [src0.hi16 : src1.hi16] (src1 -> low half)
#define PERM_LO 0x05040100u

__device__ __forceinline__ unsigned short bf_hi(float x) {
    unsigned u = __float_as_uint(x);
    return (unsigned short)((u + 0x7fffu + ((u >> 16) & 1u)) >> 16);
}
__device__ __forceinline__ void bf_split(float x, unsigned short& h, unsigned short& l) {
    unsigned u  = __float_as_uint(x);
    unsigned hu = (u + 0x7fffu + ((u >> 16) & 1u)) >> 16;
    h = (unsigned short)hu;
    l = bf_hi(x - __uint_as_float(hu << 16));
}
__device__ __forceinline__ void unpack4(uint4 u, ushort4& h, ushort4& l) {
    h = make_ushort4((unsigned short)(u.x >> 16), (unsigned short)(u.y >> 16),
                     (unsigned short)(u.z >> 16), (unsigned short)(u.w >> 16));
    l = make_ushort4((unsigned short)(u.x & 0xffff), (unsigned short)(u.y & 0xffff),
                     (unsigned short)(u.z & 0xffff), (unsigned short)(u.w & 0xffff));
}
__device__ __forceinline__ void unpack8(uint4 a, uint4 b, uint4& h, uint4& l) {
    h = make_uint4(__builtin_amdgcn_perm(a.y, a.x, PERM_HI),
                   __builtin_amdgcn_perm(a.w, a.z, PERM_HI),
                   __builtin_amdgcn_perm(b.y, b.x, PERM_HI),
                   __builtin_amdgcn_perm(b.w, b.z, PERM_HI));
    l = make_uint4(__builtin_amdgcn_perm(a.y, a.x, PERM_LO),
                   __builtin_amdgcn_perm(a.w, a.z, PERM_LO),
                   __builtin_amdgcn_perm(b.y, b.x, PERM_LO),
                   __builtin_amdgcn_perm(b.w, b.z, PERM_LO));
}
__device__ __forceinline__ short8 as_s8(uint4 u) {
    union { uint4 u; short8 s; } x; x.u = u; return x.s;
}

// DPP cross-lane (16-lane row) reductions — full-rate VALU, no LDS.
template<int CTRL>
__device__ __forceinline__ float dpp_mov(float x) {
    return __int_as_float(__builtin_amdgcn_update_dpp(
        0, __float_as_int(x), CTRL, 0xF, 0xF, true));
}
__device__ __forceinline__ float red16_max(float x) {
    x = fmaxf(x, dpp_mov<0xB1>(x));
    x = fmaxf(x, dpp_mov<0x4E>(x));
    x = fmaxf(x, dpp_mov<0x141>(x));
    x = fmaxf(x, dpp_mov<0x140>(x));
    return x;
}
__device__ __forceinline__ float red16_sum(float x) {
    x += dpp_mov<0xB1>(x);
    x += dpp_mov<0x4E>(x);
    x += dpp_mov<0x141>(x);
    x += dpp_mov<0x140>(x);
    return x;
}

// ---------------------------------------------------------------------------
// wprep: W[512k][512n] fp32 -> Wt hi/lo bf16 in [n][k] layout (B-frag layout).
// ---------------------------------------------------------------------------
__global__ __launch_bounds__(256)
void wprep(const float* __restrict__ WQ, const float* __restrict__ WK,
           const float* __restrict__ WV, unsigned short* __restrict__ wt)
{
    __shared__ float T[64][68];
    const int z = blockIdx.z;
    const float* W = (z == 0) ? WQ : (z == 1) ? WK : WV;
    unsigned short* Wth = wt + (size_t)z * 524288;
    unsigned short* Wtl = Wth + 262144;
    const int k0 = blockIdx.x * 64, n0 = blockIdx.y * 64;
    const int t = threadIdx.x;
    #pragma unroll
    for (int e = 0; e < 4; ++e) {
        int f = e * 256 + t, r = f >> 4, c4 = (f & 15) << 2;
        *(float4*)&T[r][c4] = *(const float4*)&W[(size_t)(k0 + r) * 512 + n0 + c4];
    }
    __syncthreads();
    #pragma unroll
    for (int e = 0; e < 4; ++e) {
        int f = e * 256 + t, nr = f >> 4, kc4 = (f & 15) << 2;
        ushort4 h, l;
        bf_split(T[kc4 + 0][nr], h.x, l.x);
        bf_split(T[kc4 + 1][nr], h.y, l.y);
        bf_split(T[kc4 + 2][nr], h.z, l.z);
        bf_split(T[kc4 + 3][nr], h.w, l.w);
        *(ushort4*)&Wth[(size_t)(n0 + nr) * 512 + k0 + kc4] = h;
        *(ushort4*)&Wtl[(size_t)(n0 + nr) * 512 + k0 + kc4] = l;
    }
}

// ---------------------------------------------------------------------------
// proj_mfma: C = X@W, split-bf16 MFMA. NO LDS, NO barriers: A and W loaded
// directly from global in MFMA fragment layout (W pre-split by wprep, A
// split in-register, truncated-hi). 128x128 block = 4 waves (2x2), wave
// tile 64x64, BK=32. XCD swizzle: the 4 n-blocks sharing m0 sit stride-8
// in linear id -> same XCD -> X tile re-reads hit per-XCD L2.
// z<2 (q,k): 3-pass split; z=2 (v): 1-pass hi-only.
// Outputs: q,k packed (hi<<16|lo) uint [B,H,L,D]; v ushort [B,H,D,L].
// q pre-scaled by 0.125*log2(e).
// ---------------------------------------------------------------------------
__global__ __launch_bounds__(256)
void proj_mfma(const float* __restrict__ Qin, const float* __restrict__ Kin,
               const float* __restrict__ Vin, const unsigned short* __restrict__ wt,
               unsigned int* __restrict__ qhl, unsigned int* __restrict__ khl,
               unsigned short* __restrict__ vh)
{
    // swizzle: lid -> (xcd, g); n = g&3; u = (g>>2)*8 + xcd -> z, m
    const int lid = blockIdx.x;
    const int xcd = lid & 7, g = lid >> 3;
    const int n_blk = g & 3;
    const int uu = (g >> 2) * 8 + xcd;      // 0..191
    const int z = uu >> 6;                  // 0..2
    const int m_blk = uu & 63;
    const int m0 = m_blk * 128, n0 = n_blk * 128;
    const bool full = (z < 2);
    const float* X = (z == 0) ? Qin : (z == 1) ? Kin : Vin;
    const unsigned short* Wth = wt + (size_t)z * 524288;
    const unsigned short* Wtl = Wth + 262144;

    const int t = threadIdx.x, lane = t & 63, w = t >> 6;
    const int wm = w & 1, wn = w >> 1;
    const int lm = lane & 15, lq = lane >> 4;

    const float*          Ap  = X   + (size_t)(m0 + wm * 64 + lm) * 512 + lq * 8;
    const unsigned short* Bhp = Wth + (size_t)(n0 + wn * 64 + lm) * 512 + lq * 8;
    const unsigned short* Blp = Wtl + (size_t)(n0 + wn * 64 + lm) * 512 + lq * 8;

    f32x4 acc[4][4];
    #pragma unroll
    for (int i = 0; i < 4; ++i)
        #pragma unroll
        for (int j = 0; j < 4; ++j) acc[i][j] = 0.f;

    #pragma unroll 1
    for (int k0 = 0; k0 < 512; k0 += 32) {
        short8 a_h[4], a_l[4];
        uint4  bh[4], bl[4];
        #pragma unroll
        for (int ni = 0; ni < 4; ++ni) {
            bh[ni] = *(const uint4*)(Bhp + ni * (16 * 512) + k0);
            if (full) bl[ni] = *(const uint4*)(Blp + ni * (16 * 512) + k0);
        }
        #pragma unroll
        for (int mi = 0; mi < 4; ++mi) {
            float4 f0 = *(const float4*)(Ap + (size_t)mi * (16 * 512) + k0);
            float4 f1 = *(const float4*)(Ap + (size_t)mi * (16 * 512) + k0 + 4);
            uint u0 = __float_as_uint(f0.x), u1 = __float_as_uint(f0.y),
                 u2 = __float_as_uint(f0.z), u3 = __float_as_uint(f0.w),
                 u4 = __float_as_uint(f1.x), u5 = __float_as_uint(f1.y),
                 u6 = __float_as_uint(f1.z), u7 = __float_as_uint(f1.w);
            a_h[mi] = as_s8(make_uint4(__builtin_amdgcn_perm(u1, u0, PERM_HI),
                                       __builtin_amdgcn_perm(u3, u2, PERM_HI),
                                       __builtin_amdgcn_perm(u5, u4, PERM_HI),
                                       __builtin_amdgcn_perm(u7, u6, PERM_HI)));
            if (full) {
                float r0 = f0.x - __uint_as_float(u0 & 0xffff0000u);
                float r1 = f0.y - __uint_as_float(u1 & 0xffff0000u);
                float r2 = f0.z - __uint_as_float(u2 & 0xffff0000u);
                float r3 = f0.w - __uint_as_float(u3 & 0xffff0000u);
                float r4 = f1.x - __uint_as_float(u4 & 0xffff0000u);
                float r5 = f1.y - __uint_as_float(u5 & 0xffff0000u);
                float r6 = f1.z - __uint_as_float(u6 & 0xffff0000u);
                float r7 = f1.w - __uint_as_float(u7 & 0xffff0000u);
                a_l[mi] = as_s8(make_uint4(
                    __builtin_amdgcn_perm(__float_as_uint(r1), __float_as_uint(r0), PERM_HI),
                    __builtin_amdgcn_perm(__float_as_uint(r3), __float_as_uint(r2), PERM_HI),
                    __builtin_amdgcn_perm(__float_as_uint(r5), __float_as_uint(r4), PERM_HI),
                    __builtin_amdgcn_perm(__float_as_uint(r7), __float_as_uint(r6), PERM_HI)));
            }
        }
        #pragma unroll
        for (int ni = 0; ni < 4; ++ni) {
            short8 b_h = as_s8(bh[ni]);
            if (full) {
                short8 b_l = as_s8(bl[ni]);
                #pragma unroll
                for (int mi = 0; mi < 4; ++mi) {
                    acc[mi][ni] = MFMA16(a_l[mi], b_h, acc[mi][ni]);
                    acc[mi][ni] = MFMA16(a_h[mi], b_l, acc[mi][ni]);
                    acc[mi][ni] = MFMA16(a_h[mi], b_h, acc[mi][ni]);
                }
            } else {
                #pragma unroll
                for (int mi = 0; mi < 4; ++mi)
                    acc[mi][ni] = MFMA16(a_h[mi], b_h, acc[mi][ni]);
            }
        }
    }

    if (z < 2) {
        unsigned int* o = (z == 0) ? qhl : khl;
        const float sc = (z == 0) ? 0.18033688011112042f : 1.0f;  // 0.125*log2(e)
        #pragma unroll
        for (int mi = 0; mi < 4; ++mi)
            #pragma unroll
            for (int ni = 0; ni < 4; ++ni) {
                int n_abs = n0 + wn * 64 + ni * 16 + lm;
                int hd = n_abs >> 6, d = n_abs & 63;
                #pragma unroll
                for (int r = 0; r < 4; ++r) {
                    int m_abs = m0 + wm * 64 + mi * 16 + lq * 4 + r;
                    int b = m_abs >> 10, li = m_abs & 1023;
                    unsigned short hv, lv;
                    bf_split(acc[mi][ni][r] * sc, hv, lv);
                    o[(((size_t)b * NHEAD + hd) * LEN + li) * HDIM + d] =
                        ((unsigned)hv << 16) | lv;
                }
            }
    } else {
        #pragma unroll
        for (int mi = 0; mi < 4; ++mi) {
            int m_base = m0 + wm * 64 + mi * 16 + lq * 4;
            int b = m_base >> 10, l0 = m_base & 1023;
            #pragma unroll
            for (int ni = 0; ni < 4; ++ni) {
                int n_abs = n0 + wn * 64 + ni * 16 + lm;
                int hd = n_abs >> 6, d = n_abs & 63;
                ushort4 hv = make_ushort4(bf_hi(acc[mi][ni][0]), bf_hi(acc[mi][ni][1]),
                                          bf_hi(acc[mi][ni][2]), bf_hi(acc[mi][ni][3]));
                *(ushort4*)&vh[(((size_t)b * NHEAD + hd) * HDIM + d) * LEN + l0] = hv;
            }
        }
    }
}

// ---------------------------------------------------------------------------
// attn_mfma: causal flash attention. Block = 128 q rows (4 waves x 32).
// LDS 36.9 KB (4 blocks/CU): P aliases the K region (3rd barrier guards it).
// K staging: packed uint4 loads -> v_perm unpack -> conflict-free 16B writes.
// (unchanged from R5)
// ---------------------------------------------------------------------------
__global__ __launch_bounds__(256)
void attn_mfma(const unsigned int* __restrict__ qhl, const unsigned int* __restrict__ khl,
               const unsigned short* __restrict__ vth, float* __restrict__ out)
{
    __shared__ unsigned short sm[18432];          // 36,864 B
    unsigned short* Kh  = sm;                     // 64*72 = 4608
    unsigned short* Kl  = sm + 4608;              // 64*72
    unsigned short* Pb  = sm;                     // 128*72 = 9216 (ALIASES Kh+Kl)
    unsigned short* Vt  = sm + 9216;              // 64*72  [d][key]
    unsigned short* Qsh = sm;                     // staging overlay
    unsigned short* Qsl = sm + 9216;

    const int t = threadIdx.x, lane = t & 63, w = t >> 6;
    const int lm = lane & 15, lq = lane >> 4;
    const int bx = blockIdx.x;
    const int qt = 7 - (bx >> 6);                 // heavy tiles dispatch first
    const int bh = bx & 63;
    const size_t base = (size_t)bh * LEN * HDIM;
    const unsigned int*   qb = qhl + base;
    const unsigned int*   kb = khl + base;
    const unsigned short* vb = vth + base;        // [d][l]
    const int Q0  = qt * 128;
    const int Q0w = Q0 + w * 32;

    // ---- stage Q (packed), pull split frags to registers ----
    #pragma unroll
    for (int e = 0; e < 8; ++e) {
        int f = e * 256 + t, r = f >> 4, c4 = (f & 15) << 2;
        uint4 u = *(const uint4*)&qb[(size_t)(Q0 + r) * 64 + c4];
        ushort4 h, l;
        unpack4(u, h, l);
        *(ushort4*)&Qsh[r * 72 + c4] = h;
        *(ushort4*)&Qsl[r * 72 + c4] = l;
    }
    __syncthreads();
    short8 qfh[2][2], qfl[2][2];
    #pragma unroll
    for (int mi = 0; mi < 2; ++mi)
        #pragma unroll
        for (int ks = 0; ks < 2; ++ks) {
            int off = (w * 32 + mi * 16 + lm) * 72 + ks * 32 + lq * 8;
            qfh[mi][ks] = *(const short8*)&Qsh[off];
            qfl[mi][ks] = *(const short8*)&Qsl[off];
        }

    float m_i[2][4], l_i[2][4];
    f32x4 oacc[2][4];
    #pragma unroll
    for (int mi = 0; mi < 2; ++mi)
        #pragma unroll
        for (int r = 0; r < 4; ++r) { m_i[mi][r] = -1e30f; l_i[mi][r] = 0.f; }
    #pragma unroll
    for (int mi = 0; mi < 2; ++mi)
        #pragma unroll
        for (int nd = 0; nd < 4; ++nd) oacc[mi][nd] = 0.f;

    // staging indices: K: row kr (0..63), d-quarter kq*16; V: d-row vd_, key seg vs8
    const int kr = t >> 2, kq = t & 3;
    const int vd_ = t >> 3, vs8 = (t & 7) << 3;

    // prefetch jb = 0
    uint4 kreg[4], vreg[2];
    #pragma unroll
    for (int e = 0; e < 4; ++e)
        kreg[e] = *(const uint4*)&kb[(size_t)kr * 64 + kq * 16 + e * 4];
    #pragma unroll
    for (int e = 0; e < 2; ++e)
        vreg[e] = *(const uint4*)&vb[(size_t)(e * 32 + vd_) * LEN + vs8];

    const int jend = 2 * qt + 1;
    for (int jb = 0; jb <= jend; ++jb) {
        __syncthreads();   // B1: prev iter's P/V/frag reads done
        {
            uint4 h0, l0, h1, l1;
            unpack8(kreg[0], kreg[1], h0, l0);
            unpack8(kreg[2], kreg[3], h1, l1);
            int ko = kr * 72 + kq * 16;
            *(uint4*)&Kh[ko]     = h0;
            *(uint4*)&Kh[ko + 8] = h1;
            *(uint4*)&Kl[ko]     = l0;
            *(uint4*)&Kl[ko + 8] = l1;
            *(uint4*)&Vt[(vd_)      * 72 + vs8] = vreg[0];
            *(uint4*)&Vt[(vd_ + 32) * 72 + vs8] = vreg[1];
        }
        __syncthreads();   // B2: staging visible

        if (jb < jend) {   // prefetch next tile; overlaps all compute below
            #pragma unroll
            for (int e = 0; e < 4; ++e)
                kreg[e] = *(const uint4*)&kb[(size_t)((jb + 1) * 64 + kr) * 64 + kq * 16 + e * 4];
            #pragma unroll
            for (int e = 0; e < 2; ++e)
                vreg[e] = *(const uint4*)&vb[(size_t)(e * 32 + vd_) * LEN + (jb + 1) * 64 + vs8];
        }

        const bool active = (jb * 64 <= Q0w + 31);
        f32x4 sf[2][4];
        if (active) {
            #pragma unroll
            for (int mi = 0; mi < 2; ++mi)
                #pragma unroll
                for (int ni = 0; ni < 4; ++ni) sf[mi][ni] = 0.f;
            #pragma unroll
            for (int ks = 0; ks < 2; ++ks)
                #pragma unroll
                for (int ni = 0; ni < 4; ++ni) {
                    int off = (ni * 16 + lm) * 72 + ks * 32 + lq * 8;
                    short8 b_h = *(const short8*)&Kh[off];
                    short8 b_l = *(const short8*)&Kl[off];
                    #pragma unroll
                    for (int mi = 0; mi < 2; ++mi) {
                        sf[mi][ni] = MFMA16(qfl[mi][ks], b_h, sf[mi][ni]);
                        sf[mi][ni] = MFMA16(qfh[mi][ks], b_l, sf[mi][ni]);
                        sf[mi][ni] = MFMA16(qfh[mi][ks], b_h, sf[mi][ni]);
                    }
                }
            if (jb * 64 + 63 > Q0w) {   // causal mask near diagonal
                #pragma unroll
                for (int mi = 0; mi < 2; ++mi)
                    #pragma unroll
                    for (int ni = 0; ni < 4; ++ni) {
                        int key = jb * 64 + ni * 16 + lm;
                        #pragma unroll
                        for (int r = 0; r < 4; ++r) {
                            int qi = Q0w + mi * 16 + lq * 4 + r;
                            if (key > qi) sf[mi][ni][r] = -1e30f;
                        }
                    }
            }
        }
        __syncthreads();   // B3: all K reads done — P may overwrite K region

        if (active) {
            // online softmax (base 2); rows on 16-lane groups -> DPP reduce
            #pragma unroll
            for (int mi = 0; mi < 2; ++mi)
                #pragma unroll
                for (int r = 0; r < 4; ++r) {
                    float mv = fmaxf(fmaxf(sf[mi][0][r], sf[mi][1][r]),
                                     fmaxf(sf[mi][2][r], sf[mi][3][r]));
                    mv = red16_max(mv);
                    float mo = m_i[mi][r];
                    float mn = fmaxf(mo, mv);
                    float al = __builtin_amdgcn_exp2f(mo - mn);
                    m_i[mi][r] = mn;
                    float rs = 0.f;
                    int prow = (w * 32 + mi * 16 + lq * 4 + r) * 72 + lm;
                    #pragma unroll
                    for (int ni = 0; ni < 4; ++ni) {
                        float p = __builtin_amdgcn_exp2f(sf[mi][ni][r] - mn);
                        rs += p;
                        Pb[prow + ni * 16] = bf_hi(p);
                    }
                    rs = red16_sum(rs);
                    l_i[mi][r] = l_i[mi][r] * al + rs;
                    #pragma unroll
                    for (int nd = 0; nd < 4; ++nd) oacc[mi][nd][r] *= al;
                }
            // P round-trip: same-wave rows, lgkmcnt ordering suffices
            short8 pf[2][2];
            #pragma unroll
            for (int mi = 0; mi < 2; ++mi)
                #pragma unroll
                for (int ks = 0; ks < 2; ++ks)
                    pf[mi][ks] = *(const short8*)&Pb[(w * 32 + mi * 16 + lm) * 72 + ks * 32 + lq * 8];
            #pragma unroll
            for (int ks = 0; ks < 2; ++ks)
                #pragma unroll
                for (int nd = 0; nd < 4; ++nd) {
                    short8 vf = *(const short8*)&Vt[(nd * 16 + lm) * 72 + ks * 32 + lq * 8];
                    #pragma unroll
                    for (int mi = 0; mi < 2; ++mi)
                        oacc[mi][nd] = MFMA16(pf[mi][ks], vf, oacc[mi][nd]);
                }
        }
    }

    // epilogue: divide by l, write [B, L, H*D] fp32
    const int b = bh >> 3, hd = bh & 7;
    #pragma unroll
    for (int mi = 0; mi < 2; ++mi)
        #pragma unroll
        for (int r = 0; r < 4; ++r) {
            int qrow = Q0w + mi * 16 + lq * 4 + r;
            float inv = 1.0f / l_i[mi][r];
            #pragma unroll
            for (int nd = 0; nd < 4; ++nd) {
                int d = nd * 16 + lm;
                out[((size_t)b * LEN + qrow) * (NHEAD * HDIM) + hd * 64 + d] =
                    oacc[mi][nd][r] * inv;
            }
        }
}

// ---------------------------------------------------------------------------
extern "C" void kernel_launch(void* const* d_in, const int* in_sizes, int n_in,
                              void* d_out, int out_size, void* d_ws, size_t ws_size,
                              hipStream_t stream)
{
    const float* Qin = (const float*)d_in[0];
    const float* Kin = (const float*)d_in[1];
    const float* Vin = (const float*)d_in[2];
    const float* WQ  = (const float*)d_in[3];
    const float* WK  = (const float*)d_in[4];
    const float* WV  = (const float*)d_in[5];

    const size_t per = (size_t)BATCH * NHEAD * LEN * HDIM;   // 4,194,304 elements
    unsigned int*   qhl = (unsigned int*)d_ws;               // 16 MB
    unsigned int*   khl = qhl + per;                         // 16 MB
    unsigned short* vh  = (unsigned short*)(khl + per);      // 8 MB
    unsigned short* wt  = vh + per;                          // 3 MB   (total 43 MB)

    wprep    <<<dim3(8, 8, 3), 256, 0, stream>>>(WQ, WK, WV, wt);
    proj_mfma<<<dim3(768),     256, 0, stream>>>(Qin, Kin, Vin, wt, qhl, khl, vh);
    attn_mfma<<<dim3(512),     256, 0, stream>>>(qhl, khl, vh, (float*)d_out);
}

// Round 7
// 188.010 us; speedup vs baseline: 1.3306x; 1.3306x over previous
//
#include <hip/hip_runtime.h>
#include <cstddef>

#define LEN    1024
#define DIN    512
#define NHEAD  8
#define HDIM   64
#define BATCH  8

typedef __attribute__((ext_vector_type(8))) short  short8;
typedef __attribute__((ext_vector_type(4))) float  f32x4;

#define MFMA16(a, b, c) __builtin_amdgcn_mfma_f32_16x16x32_bf16((a), (b), (c), 0, 0, 0)
#define PERM_HI 0x07060302u
#define PERM_LO 0x05040100u

__device__ __forceinline__ unsigned short bf_hi(float x) {
    unsigned u = __float_as_uint(x);
    return (unsigned short)((u + 0x7fffu + ((u >> 16) & 1u)) >> 16);
}
__device__ __forceinline__ void bf_split(float x, unsigned short& h, unsigned short& l) {
    unsigned u  = __float_as_uint(x);
    unsigned hu = (u + 0x7fffu + ((u >> 16) & 1u)) >> 16;
    h = (unsigned short)hu;
    l = bf_hi(x - __uint_as_float(hu << 16));
}
__device__ __forceinline__ void unpack4(uint4 u, ushort4& h, ushort4& l) {
    h = make_ushort4((unsigned short)(u.x >> 16), (unsigned short)(u.y >> 16),
                     (unsigned short)(u.z >> 16), (unsigned short)(u.w >> 16));
    l = make_ushort4((unsigned short)(u.x & 0xffff), (unsigned short)(u.y & 0xffff),
                     (unsigned short)(u.z & 0xffff), (unsigned short)(u.w & 0xffff));
}
__device__ __forceinline__ void unpack8(uint4 a, uint4 b, uint4& h, uint4& l) {
    h = make_uint4(__builtin_amdgcn_perm(a.y, a.x, PERM_HI),
                   __builtin_amdgcn_perm(a.w, a.z, PERM_HI),
                   __builtin_amdgcn_perm(b.y, b.x, PERM_HI),
                   __builtin_amdgcn_perm(b.w, b.z, PERM_HI));
    l = make_uint4(__builtin_amdgcn_perm(a.y, a.x, PERM_LO),
                   __builtin_amdgcn_perm(a.w, a.z, PERM_LO),
                   __builtin_amdgcn_perm(b.y, b.x, PERM_LO),
                   __builtin_amdgcn_perm(b.w, b.z, PERM_LO));
}

// DPP cross-lane (16-lane row) reductions — full-rate VALU, no LDS.
template<int CTRL>
__device__ __forceinline__ float dpp_mov(float x) {
    return __int_as_float(__builtin_amdgcn_update_dpp(
        0, __float_as_int(x), CTRL, 0xF, 0xF, true));
}
__device__ __forceinline__ float red16_max(float x) {
    x = fmaxf(x, dpp_mov<0xB1>(x));
    x = fmaxf(x, dpp_mov<0x4E>(x));
    x = fmaxf(x, dpp_mov<0x141>(x));
    x = fmaxf(x, dpp_mov<0x140>(x));
    return x;
}
__device__ __forceinline__ float red16_sum(float x) {
    x += dpp_mov<0xB1>(x);
    x += dpp_mov<0x4E>(x);
    x += dpp_mov<0x141>(x);
    x += dpp_mov<0x140>(x);
    return x;
}

// ---------------------------------------------------------------------------
// wprep: W[512k][512n] fp32 -> Wt hi/lo bf16 in [n][k] layout (B-frag layout).
// ---------------------------------------------------------------------------
__global__ __launch_bounds__(256)
void wprep(const float* __restrict__ WQ, const float* __restrict__ WK,
           const float* __restrict__ WV, unsigned short* __restrict__ wt)
{
    __shared__ float T[64][68];
    const int z = blockIdx.z;
    const float* W = (z == 0) ? WQ : (z == 1) ? WK : WV;
    unsigned short* Wth = wt + (size_t)z * 524288;
    unsigned short* Wtl = Wth + 262144;
    const int k0 = blockIdx.x * 64, n0 = blockIdx.y * 64;
    const int t = threadIdx.x;
    #pragma unroll
    for (int e = 0; e < 4; ++e) {
        int f = e * 256 + t, r = f >> 4, c4 = (f & 15) << 2;
        *(float4*)&T[r][c4] = *(const float4*)&W[(size_t)(k0 + r) * 512 + n0 + c4];
    }
    __syncthreads();
    #pragma unroll
    for (int e = 0; e < 4; ++e) {
        int f = e * 256 + t, nr = f >> 4, kc4 = (f & 15) << 2;
        ushort4 h, l;
        bf_split(T[kc4 + 0][nr], h.x, l.x);
        bf_split(T[kc4 + 1][nr], h.y, l.y);
        bf_split(T[kc4 + 2][nr], h.z, l.z);
        bf_split(T[kc4 + 3][nr], h.w, l.w);
        *(ushort4*)&Wth[(size_t)(n0 + nr) * 512 + k0 + kc4] = h;
        *(ushort4*)&Wtl[(size_t)(n0 + nr) * 512 + k0 + kc4] = l;
    }
}

// ---------------------------------------------------------------------------
// proj_mfma (R5 LDS structure): C = X@W, split-bf16 MFMA. 128x128 tile, BK=32.
// __launch_bounds__(256,3): cap regs so 3 blocks/CU fit -> 768 blocks = one
// full round of the machine (was 2 blocks/CU -> 1.5 rounds, half-idle tail).
// z<2 (q,k): 3-pass split; z=2 (v): 1-pass hi-only.
// Outputs: q,k packed (hi<<16|lo) uint [B,H,L,D]; v ushort [B,H,D,L].
// q pre-scaled by 0.125*log2(e).
// ---------------------------------------------------------------------------
#define PSTR 40   // LDS row stride in ushorts

__global__ __launch_bounds__(256, 3)
void proj_mfma(const float* __restrict__ Qin, const float* __restrict__ Kin,
               const float* __restrict__ Vin, const unsigned short* __restrict__ wt,
               unsigned int* __restrict__ qhl, unsigned int* __restrict__ khl,
               unsigned short* __restrict__ vh)
{
    __shared__ unsigned short Ah[128 * PSTR], Al[128 * PSTR],
                              Bh[128 * PSTR], Bl[128 * PSTR];
    const int z = blockIdx.z;
    const bool full = (z < 2);
    const float* X = (z == 0) ? Qin : (z == 1) ? Kin : Vin;
    const unsigned short* Wth = wt + (size_t)z * 524288;
    const unsigned short* Wtl = Wth + 262144;

    const int t = threadIdx.x, lane = t & 63, w = t >> 6;
    const int wm = w & 1, wn = w >> 1;
    const int m0 = blockIdx.x * 128, n0 = blockIdx.y * 128;
    const int lm = lane & 15, lq = lane >> 4;
    const int ar = t >> 1, ak = (t & 1) * 16;

    const float* Xp = X + (size_t)(m0 + ar) * 512 + ak;
    const unsigned short* Bph = Wth + (size_t)(n0 + ar) * 512 + ak;
    const unsigned short* Bpl = Wtl + (size_t)(n0 + ar) * 512 + ak;

    f32x4 acc[4][4];
    #pragma unroll
    for (int i = 0; i < 4; ++i)
        #pragma unroll
        for (int j = 0; j < 4; ++j) acc[i][j] = 0.f;

    // prefetch k0 = 0
    float4 av[4];
    uint4 bh0, bh1, bl0, bl1;
    #pragma unroll
    for (int e = 0; e < 4; ++e) av[e] = *(const float4*)(Xp + e * 4);
    bh0 = *(const uint4*)(Bph);
    bh1 = *(const uint4*)(Bph + 8);
    if (full) { bl0 = *(const uint4*)(Bpl); bl1 = *(const uint4*)(Bpl + 8); }

    for (int k0 = 0; k0 < 512; k0 += 32) {
        __syncthreads();                       // prev iter's frag reads done
        // ---- A: rounded-hi split, 16B conflict-free writes ----
        {
            const float* ff = (const float*)&av[0];   // av[4] is contiguous
            uint hw[16];
            #pragma unroll
            for (int i = 0; i < 16; ++i) hw[i] = __float_as_uint(ff[i]) & 0xffff0000u;
            uint4 ahv  = make_uint4(__builtin_amdgcn_perm(hw[1],  hw[0],  PERM_HI),
                                    __builtin_amdgcn_perm(hw[3],  hw[2],  PERM_HI),
                                    __builtin_amdgcn_perm(hw[5],  hw[4],  PERM_HI),
                                    __builtin_amdgcn_perm(hw[7],  hw[6],  PERM_HI));
            uint4 ahv2 = make_uint4(__builtin_amdgcn_perm(hw[9],  hw[8],  PERM_HI),
                                    __builtin_amdgcn_perm(hw[11], hw[10], PERM_HI),
                                    __builtin_amdgcn_perm(hw[13], hw[12], PERM_HI),
                                    __builtin_amdgcn_perm(hw[15], hw[14], PERM_HI));
            *(uint4*)&Ah[ar * PSTR + ak]     = ahv;
            *(uint4*)&Ah[ar * PSTR + ak + 8] = ahv2;
            if (full) {
                uint lo[8];
                #pragma unroll
                for (int i = 0; i < 8; ++i) {
                    float r0 = ff[2*i]   - __uint_as_float(hw[2*i]);
                    float r1 = ff[2*i+1] - __uint_as_float(hw[2*i+1]);
                    lo[i] = ((uint)bf_hi(r1) << 16) | bf_hi(r0);
                }
                *(uint4*)&Al[ar * PSTR + ak]     = make_uint4(lo[0], lo[1], lo[2], lo[3]);
                *(uint4*)&Al[ar * PSTR + ak + 8] = make_uint4(lo[4], lo[5], lo[6], lo[7]);
            }
        }
        // ---- B: straight copies ----
        *(uint4*)&Bh[ar * PSTR + ak]     = bh0;
        *(uint4*)&Bh[ar * PSTR + ak + 8] = bh1;
        if (full) {
            *(uint4*)&Bl[ar * PSTR + ak]     = bl0;
            *(uint4*)&Bl[ar * PSTR + ak + 8] = bl1;
        }
        __syncthreads();

        if (k0 + 32 < 512) {                   // prefetch next (overlaps MFMA)
            #pragma unroll
            for (int e = 0; e < 4; ++e) av[e] = *(const float4*)(Xp + k0 + 32 + e * 4);
            bh0 = *(const uint4*)(Bph + k0 + 32);
            bh1 = *(const uint4*)(Bph + k0 + 40);
            if (full) {
                bl0 = *(const uint4*)(Bpl + k0 + 32);
                bl1 = *(const uint4*)(Bpl + k0 + 40);
            }
        }

        short8 a_h[4], a_l[4];
        #pragma unroll
        for (int mi = 0; mi < 4; ++mi) {
            int off = (wm * 64 + mi * 16 + lm) * PSTR + lq * 8;
            a_h[mi] = *(const short8*)&Ah[off];
            if (full) a_l[mi] = *(const short8*)&Al[off];
        }
        #pragma unroll
        for (int ni = 0; ni < 4; ++ni) {
            int off = (wn * 64 + ni * 16 + lm) * PSTR + lq * 8;
            short8 b_h = *(const short8*)&Bh[off];
            if (full) {
                short8 b_l = *(const short8*)&Bl[off];
                #pragma unroll
                for (int mi = 0; mi < 4; ++mi) {
                    acc[mi][ni] = MFMA16(a_l[mi], b_h, acc[mi][ni]);
                    acc[mi][ni] = MFMA16(a_h[mi], b_l, acc[mi][ni]);
                    acc[mi][ni] = MFMA16(a_h[mi], b_h, acc[mi][ni]);
                }
            } else {
                #pragma unroll
                for (int mi = 0; mi < 4; ++mi)
                    acc[mi][ni] = MFMA16(a_h[mi], b_h, acc[mi][ni]);
            }
        }
    }

    if (z < 2) {
        unsigned int* o = (z == 0) ? qhl : khl;
        const float sc = (z == 0) ? 0.18033688011112042f : 1.0f;  // 0.125*log2(e)
        #pragma unroll
        for (int mi = 0; mi < 4; ++mi)
            #pragma unroll
            for (int ni = 0; ni < 4; ++ni) {
                int n_abs = n0 + wn * 64 + ni * 16 + lm;
                int hd = n_abs >> 6, d = n_abs & 63;
                #pragma unroll
                for (int r = 0; r < 4; ++r) {
                    int m_abs = m0 + wm * 64 + mi * 16 + lq * 4 + r;
                    int b = m_abs >> 10, li = m_abs & 1023;
                    unsigned short hv, lv;
                    bf_split(acc[mi][ni][r] * sc, hv, lv);
                    o[(((size_t)b * NHEAD + hd) * LEN + li) * HDIM + d] =
                        ((unsigned)hv << 16) | lv;
                }
            }
    } else {
        #pragma unroll
        for (int mi = 0; mi < 4; ++mi) {
            int m_base = m0 + wm * 64 + mi * 16 + lq * 4;
            int b = m_base >> 10, l0 = m_base & 1023;
            #pragma unroll
            for (int ni = 0; ni < 4; ++ni) {
                int n_abs = n0 + wn * 64 + ni * 16 + lm;
                int hd = n_abs >> 6, d = n_abs & 63;
                ushort4 hv = make_ushort4(bf_hi(acc[mi][ni][0]), bf_hi(acc[mi][ni][1]),
                                          bf_hi(acc[mi][ni][2]), bf_hi(acc[mi][ni][3]));
                *(ushort4*)&vh[(((size_t)b * NHEAD + hd) * HDIM + d) * LEN + l0] = hv;
            }
        }
    }
}

// ---------------------------------------------------------------------------
// attn_mfma: causal flash attention. Block = 128 q rows (4 waves x 32).
// LDS 36.9 KB; P aliases the K region (B3 guards it).
// Complement-paired grid: consecutive blocks (2i,2i+1) carry qt = a and 7-a,
// so any 2 dispatch-consecutive blocks sum to 18 tile-steps (uniform load
// for the 2 co-resident blocks/CU).
// ---------------------------------------------------------------------------
__global__ __launch_bounds__(256)
void attn_mfma(const unsigned int* __restrict__ qhl, const unsigned int* __restrict__ khl,
               const unsigned short* __restrict__ vth, float* __restrict__ out)
{
    __shared__ unsigned short sm[18432];          // 36,864 B
    unsigned short* Kh  = sm;                     // 64*72 = 4608
    unsigned short* Kl  = sm + 4608;              // 64*72
    unsigned short* Pb  = sm;                     // 128*72 = 9216 (ALIASES Kh+Kl)
    unsigned short* Vt  = sm + 9216;              // 64*72  [d][key]
    unsigned short* Qsh = sm;                     // staging overlay
    unsigned short* Qsl = sm + 9216;

    const int t = threadIdx.x, lane = t & 63, w = t >> 6;
    const int lm = lane & 15, lq = lane >> 4;
    const int bx = blockIdx.x;
    const int idx = bx >> 1, par = bx & 1;
    const int bh = idx & 63;
    const int a  = idx >> 6;                      // 0..3
    const int qt = par ? (7 - a) : a;             // complement pairs
    const size_t base = (size_t)bh * LEN * HDIM;
    const unsigned int*   qb = qhl + base;
    const unsigned int*   kb = khl + base;
    const unsigned short* vb = vth + base;        // [d][l]
    const int Q0  = qt * 128;
    const int Q0w = Q0 + w * 32;

    // ---- stage Q (packed), pull split frags to registers ----
    #pragma unroll
    for (int e = 0; e < 8; ++e) {
        int f = e * 256 + t, r = f >> 4, c4 = (f & 15) << 2;
        uint4 u = *(const uint4*)&qb[(size_t)(Q0 + r) * 64 + c4];
        ushort4 h, l;
        unpack4(u, h, l);
        *(ushort4*)&Qsh[r * 72 + c4] = h;
        *(ushort4*)&Qsl[r * 72 + c4] = l;
    }
    __syncthreads();
    short8 qfh[2][2], qfl[2][2];
    #pragma unroll
    for (int mi = 0; mi < 2; ++mi)
        #pragma unroll
        for (int ks = 0; ks < 2; ++ks) {
            int off = (w * 32 + mi * 16 + lm) * 72 + ks * 32 + lq * 8;
            qfh[mi][ks] = *(const short8*)&Qsh[off];
            qfl[mi][ks] = *(const short8*)&Qsl[off];
        }

    float m_i[2][4], l_i[2][4];
    f32x4 oacc[2][4];
    #pragma unroll
    for (int mi = 0; mi < 2; ++mi)
        #pragma unroll
        for (int r = 0; r < 4; ++r) { m_i[mi][r] = -1e30f; l_i[mi][r] = 0.f; }
    #pragma unroll
    for (int mi = 0; mi < 2; ++mi)
        #pragma unroll
        for (int nd = 0; nd < 4; ++nd) oacc[mi][nd] = 0.f;

    // staging indices: K: row kr (0..63), d-quarter kq*16; V: d-row vd_, key seg vs8
    const int kr = t >> 2, kq = t & 3;
    const int vd_ = t >> 3, vs8 = (t & 7) << 3;

    // prefetch jb = 0
    uint4 kreg[4], vreg[2];
    #pragma unroll
    for (int e = 0; e < 4; ++e)
        kreg[e] = *(const uint4*)&kb[(size_t)kr * 64 + kq * 16 + e * 4];
    #pragma unroll
    for (int e = 0; e < 2; ++e)
        vreg[e] = *(const uint4*)&vb[(size_t)(e * 32 + vd_) * LEN + vs8];

    const int jend = 2 * qt + 1;
    for (int jb = 0; jb <= jend; ++jb) {
        __syncthreads();   // B1: prev iter's P/V/frag reads done
        {
            uint4 h0, l0, h1, l1;
            unpack8(kreg[0], kreg[1], h0, l0);
            unpack8(kreg[2], kreg[3], h1, l1);
            int ko = kr * 72 + kq * 16;
            *(uint4*)&Kh[ko]     = h0;
            *(uint4*)&Kh[ko + 8] = h1;
            *(uint4*)&Kl[ko]     = l0;
            *(uint4*)&Kl[ko + 8] = l1;
            *(uint4*)&Vt[(vd_)      * 72 + vs8] = vreg[0];
            *(uint4*)&Vt[(vd_ + 32) * 72 + vs8] = vreg[1];
        }
        __syncthreads();   // B2: staging visible

        if (jb < jend) {   // prefetch next tile; overlaps all compute below
            #pragma unroll
            for (int e = 0; e < 4; ++e)
                kreg[e] = *(const uint4*)&kb[(size_t)((jb + 1) * 64 + kr) * 64 + kq * 16 + e * 4];
            #pragma unroll
            for (int e = 0; e < 2; ++e)
                vreg[e] = *(const uint4*)&vb[(size_t)(e * 32 + vd_) * LEN + (jb + 1) * 64 + vs8];
        }

        const bool active = (jb * 64 <= Q0w + 31);
        f32x4 sf[2][4];
        if (active) {
            #pragma unroll
            for (int mi = 0; mi < 2; ++mi)
                #pragma unroll
                for (int ni = 0; ni < 4; ++ni) sf[mi][ni] = 0.f;
            #pragma unroll
            for (int ks = 0; ks < 2; ++ks)
                #pragma unroll
                for (int ni = 0; ni < 4; ++ni) {
                    int off = (ni * 16 + lm) * 72 + ks * 32 + lq * 8;
                    short8 b_h = *(const short8*)&Kh[off];
                    short8 b_l = *(const short8*)&Kl[off];
                    #pragma unroll
                    for (int mi = 0; mi < 2; ++mi) {
                        sf[mi][ni] = MFMA16(qfl[mi][ks], b_h, sf[mi][ni]);
                        sf[mi][ni] = MFMA16(qfh[mi][ks], b_l, sf[mi][ni]);
                        sf[mi][ni] = MFMA16(qfh[mi][ks], b_h, sf[mi][ni]);
                    }
                }
            if (jb * 64 + 63 > Q0w) {   // causal mask near diagonal
                #pragma unroll
                for (int mi = 0; mi < 2; ++mi)
                    #pragma unroll
                    for (int ni = 0; ni < 4; ++ni) {
                        int key = jb * 64 + ni * 16 + lm;
                        #pragma unroll
                        for (int r = 0; r < 4; ++r) {
                            int qi = Q0w + mi * 16 + lq * 4 + r;
                            if (key > qi) sf[mi][ni][r] = -1e30f;
                        }
                    }
            }
        }
        __syncthreads();   // B3: all K reads done — P may overwrite K region

        if (active) {
            // online softmax (base 2); rows on 16-lane groups -> DPP reduce
            #pragma unroll
            for (int mi = 0; mi < 2; ++mi)
                #pragma unroll
                for (int r = 0; r < 4; ++r) {
                    float mv = fmaxf(fmaxf(sf[mi][0][r], sf[mi][1][r]),
                                     fmaxf(sf[mi][2][r], sf[mi][3][r]));
                    mv = red16_max(mv);
                    float mo = m_i[mi][r];
                    float mn = fmaxf(mo, mv);
                    float al = __builtin_amdgcn_exp2f(mo - mn);
                    m_i[mi][r] = mn;
                    float rs = 0.f;
                    int prow = (w * 32 + mi * 16 + lq * 4 + r) * 72 + lm;
                    #pragma unroll
                    for (int ni = 0; ni < 4; ++ni) {
                        float p = __builtin_amdgcn_exp2f(sf[mi][ni][r] - mn);
                        rs += p;
                        Pb[prow + ni * 16] = bf_hi(p);
                    }
                    rs = red16_sum(rs);
                    l_i[mi][r] = l_i[mi][r] * al + rs;
                    #pragma unroll
                    for (int nd = 0; nd < 4; ++nd) oacc[mi][nd][r] *= al;
                }
            // P round-trip: same-wave rows, lgkmcnt ordering suffices
            short8 pf[2][2];
            #pragma unroll
            for (int mi = 0; mi < 2; ++mi)
                #pragma unroll
                for (int ks = 0; ks < 2; ++ks)
                    pf[mi][ks] = *(const short8*)&Pb[(w * 32 + mi * 16 + lm) * 72 + ks * 32 + lq * 8];
            #pragma unroll
            for (int ks = 0; ks < 2; ++ks)
                #pragma unroll
                for (int nd = 0; nd < 4; ++nd) {
                    short8 vf = *(const short8*)&Vt[(nd * 16 + lm) * 72 + ks * 32 + lq * 8];
                    #pragma unroll
                    for (int mi = 0; mi < 2; ++mi)
                        oacc[mi][nd] = MFMA16(pf[mi][ks], vf, oacc[mi][nd]);
                }
        }
    }

    // epilogue: divide by l, write [B, L, H*D] fp32
    const int b = bh >> 3, hd = bh & 7;
    #pragma unroll
    for (int mi = 0; mi < 2; ++mi)
        #pragma unroll
        for (int r = 0; r < 4; ++r) {
            int qrow = Q0w + mi * 16 + lq * 4 + r;
            float inv = 1.0f / l_i[mi][r];
            #pragma unroll
            for (int nd = 0; nd < 4; ++nd) {
                int d = nd * 16 + lm;
                out[((size_t)b * LEN + qrow) * (NHEAD * HDIM) + hd * 64 + d] =
                    oacc[mi][nd][r] * inv;
            }
        }
}

// ---------------------------------------------------------------------------
extern "C" void kernel_launch(void* const* d_in, const int* in_sizes, int n_in,
                              void* d_out, int out_size, void* d_ws, size_t ws_size,
                              hipStream_t stream)
{
    const float* Qin = (const float*)d_in[0];
    const float* Kin = (const float*)d_in[1];
    const float* Vin = (const float*)d_in[2];
    const float* WQ  = (const float*)d_in[3];
    const float* WK  = (const float*)d_in[4];
    const float* WV  = (const float*)d_in[5];

    const size_t per = (size_t)BATCH * NHEAD * LEN * HDIM;   // 4,194,304 elements
    unsigned int*   qhl = (unsigned int*)d_ws;               // 16 MB
    unsigned int*   khl = qhl + per;                         // 16 MB
    unsigned short* vh  = (unsigned short*)(khl + per);      // 8 MB
    unsigned short* wt  = vh + per;                          // 3 MB   (total 43 MB)

    wprep    <<<dim3(8, 8, 3),  256, 0, stream>>>(WQ, WK, WV, wt);
    proj_mfma<<<dim3(64, 4, 3), 256, 0, stream>>>(Qin, Kin, Vin, wt, qhl, khl, vh);
    attn_mfma<<<dim3(512),      256, 0, stream>>>(qhl, khl, vh, (float*)d_out);
}